// Round 9
// baseline (508.930 us; speedup 1.0000x reference)
//
#include <hip/hip_runtime.h>
#include <hip/hip_bf16.h>

// GraphSAGE 2-layer, bf16 MFMA version.
//   L1: h   = relu([agg1|x] @ [W1l;W1r] + b1)   K=256, N=256, bf16 MFMA
//   L2: [y2|t] = h @ [W2l|W2r] (+b2 on t)       K=256, N=80,  bf16 MFMA
//   out = mean_gather(y2) + t
// R9: CSR build with ZERO global atomics (R8 showed device atomics hit the
//     memory-side fabric: 25 MB EA churn, ~40 us). Edges in 8 chunks x nodes
//     in 32 slices; LDS histograms count (pass A, fused into prep) and place
//     (pass B, k_fillcsr) edges. rank buffer + deg memset gone.

#define NN   100000
#define NNP  100096          // 782*128 = 1564*64
#define NE   800000
#define NB1  391             // ceil(NN/256)
#define NSL  3125            // nodes per slice (32 slices)
#define NCH  100000          // edges per chunk (8 chunks)

typedef unsigned short ushortT;
typedef __attribute__((ext_vector_type(8))) short bf16x8;
typedef __attribute__((ext_vector_type(4))) float f32x4;

__device__ __forceinline__ unsigned short f2b(float f) {
    unsigned u = __float_as_uint(f);
    return (unsigned short)((u + 0x7fffu + ((u >> 16) & 1u)) >> 16);
}
__device__ __forceinline__ float b2f(unsigned short v) {
    return __uint_as_float(((unsigned)v) << 16);
}
__device__ __forceinline__ void llds16(const unsigned short* g, unsigned short* s) {
    __builtin_amdgcn_global_load_lds(
        (const __attribute__((address_space(1))) void*)g,
        (__attribute__((address_space(3))) void*)s, 16, 0, 0);
}

// --------------------------------------------- prep + histogram (pass A)
// blocks [0,12500): x->bf16 cast + weight transpose/cast
// blocks [12500,12756): block (s,c) counts chunk-c edges into slice-s via
//                       LDS histogram -> deg8[c][node] (no global atomics)
__global__ __launch_bounds__(256) void k_prep(
        const float* __restrict__ x,
        const float* __restrict__ W1l, const float* __restrict__ W1r,
        const float* __restrict__ W2l, const float* __restrict__ W2r,
        ushortT* __restrict__ Ac, ushortT* __restrict__ WT1,
        ushortT* __restrict__ WT2,
        const int* __restrict__ dst, int* __restrict__ deg8) {
    __shared__ int hist[NSL];
    int bid = blockIdx.x;
    if (bid < 12500) {
        int t = bid * 256 + threadIdx.x;          // [0, NN*32)
        int row = t >> 5, c4 = t & 31;
        float4 v = *(const float4*)&x[(size_t)row * 128 + c4 * 4];
        ushortT* p = Ac + (size_t)row * 256 + 128 + c4 * 4;
        p[0] = f2b(v.x); p[1] = f2b(v.y); p[2] = f2b(v.z); p[3] = f2b(v.w);

        if (t < 65536) {                          // WT1 [256n][256k]
            int n = t >> 8, k = t & 255;
            float w = (k < 128) ? W1l[(size_t)k * 256 + n]
                                : W1r[(size_t)(k - 128) * 256 + n];
            WT1[t] = f2b(w);
        } else if (t < 65536 + 20480) {           // WT2 [80n][256k]
            int j = t - 65536;
            int n = j >> 8, k = j & 255;
            float w = (n < 40) ? W2l[(size_t)k * 40 + n]
                               : W2r[(size_t)k * 40 + (n - 40)];
            WT2[j] = f2b(w);
        }
    } else {
        int idx = bid - 12500;                    // [0,256)
        int c = idx & 7, s = idx >> 3;            // chunk (XCD-local reads), slice
        for (int i = threadIdx.x; i < NSL; i += 256) hist[i] = 0;
        __syncthreads();
        int e0 = c * NCH, lo = s * NSL;
        for (int i = threadIdx.x; i < NCH; i += 256) {
            unsigned dd = (unsigned)(dst[e0 + i] - lo);
            if (dd < (unsigned)NSL) atomicAdd(&hist[dd], 1);
        }
        __syncthreads();
        for (int i = threadIdx.x; i < NSL; i += 256)
            deg8[c * NN + lo + i] = hist[i];
    }
}

// ------------------------------------------- scan over summed chunk degs
// rp[i] = block-local exclusive prefix of deg_tot; rpp[c][i] = rp[i] +
// sum of chunks < c (fill's per-chunk base). bsum = per-block totals.
__global__ __launch_bounds__(256) void k_scan1(const int* __restrict__ deg8,
                                               int* __restrict__ rp,
                                               int* __restrict__ rpp,
                                               int* __restrict__ bsum) {
    __shared__ int s[256];
    int t = threadIdx.x;
    int i = blockIdx.x * 256 + t;
    int d8[8];
    int v = 0;
#pragma unroll
    for (int r = 0; r < 8; ++r) {
        d8[r] = (i < NN) ? deg8[r * NN + i] : 0;
        v += d8[r];
    }
    s[t] = v;
    __syncthreads();
    for (int off = 1; off < 256; off <<= 1) {
        int add = (t >= off) ? s[t - off] : 0;
        __syncthreads();
        s[t] += add;
        __syncthreads();
    }
    int ex = s[t] - v;
    if (i <= NN) rp[i] = ex;                      // i==NN: v=0 -> exclusive end
    if (i < NN) {
        int run = ex;
#pragma unroll
        for (int r = 0; r < 8; ++r) {
            rpp[r * NN + i] = run;
            run += d8[r];
        }
    }
    if (t == 255) bsum[blockIdx.x] = s[255];
}

__global__ __launch_bounds__(512) void k_scan2(int* __restrict__ bsum) {
    __shared__ int s[512];
    int t = threadIdx.x;
    int v = (t < NB1) ? bsum[t] : 0;
    s[t] = v;
    __syncthreads();
    for (int off = 1; off < 512; off <<= 1) {
        int add = (t >= off) ? s[t - off] : 0;
        __syncthreads();
        s[t] += add;
        __syncthreads();
    }
    if (t < NB1) bsum[t] = s[t] - v;              // exclusive block offsets
}

// --------------------------------------------------- CSR fill (pass B)
// block (s,c): re-scan chunk c, LDS-count slice-s nodes, place edges at
// col[bsum + rpp[c][d] + k]. bid&31 = slice -> each slice's col region is
// written by one XCD (bid%8 == s%8). No atomics, no rank buffer.
__global__ __launch_bounds__(256) void k_fillcsr(const int* __restrict__ src,
                                                 const int* __restrict__ dst,
                                                 const int* __restrict__ rpp,
                                                 const int* __restrict__ bsum,
                                                 int* __restrict__ col) {
    __shared__ int hist[NSL];
    int s = blockIdx.x & 31, c = blockIdx.x >> 5;
    for (int i = threadIdx.x; i < NSL; i += 256) hist[i] = 0;
    __syncthreads();
    int e0 = c * NCH, lo = s * NSL;
    for (int i = threadIdx.x; i < NCH; i += 256) {
        int e = e0 + i;
        int d = dst[e];
        unsigned dd = (unsigned)(d - lo);
        if (dd < (unsigned)NSL) {
            int k = atomicAdd(&hist[dd], 1);      // LDS atomic
            col[bsum[d >> 8] + rpp[c * NN + d] + k] = src[e];
        }
    }
}

// ------------------------------------------------------- mean aggregation 1
// gather bf16 x rows (A_cat[:,128:]), write bf16 mean to A_cat[:,0:128].
// One wave per node; col prefetch + __shfl bcast; 8 row-loads in flight.
__global__ __launch_bounds__(256) void k_agg1(const int* __restrict__ rp,
                                              const int* __restrict__ bsum,
                                              const int* __restrict__ col,
                                              ushortT* __restrict__ Ac) {
    int node = blockIdx.x * 4 + (threadIdx.x >> 6);
    int l = threadIdx.x & 63;
    if (node >= NN) return;
    int seg = l >> 4, dl = l & 15;
    int beg = rp[node] + bsum[node >> 8];
    int end = rp[node + 1] + bsum[(node + 1) >> 8];
    int deg = end - beg;
    float a[8] = {0.f, 0.f, 0.f, 0.f, 0.f, 0.f, 0.f, 0.f};
    for (int base = 0; base < deg; base += 64) {
        int cnt = min(64, deg - base);
        int cv = col[beg + base + min(l, cnt - 1)];
        for (int j = 0; j < cnt; j += 8) {
            int e0 = j + seg, e1 = j + 4 + seg;
            int i0 = __shfl(cv, min(e0, cnt - 1));
            int i1 = __shfl(cv, min(e1, cnt - 1));
            bf16x8 v0 = {0, 0, 0, 0, 0, 0, 0, 0};
            bf16x8 v1 = {0, 0, 0, 0, 0, 0, 0, 0};
            if (e0 < cnt) v0 = *(const bf16x8*)(Ac + (size_t)i0 * 256 + 128 + dl * 8);
            if (e1 < cnt) v1 = *(const bf16x8*)(Ac + (size_t)i1 * 256 + 128 + dl * 8);
#pragma unroll
            for (int i = 0; i < 8; ++i)
                a[i] += b2f((unsigned short)v0[i]) + b2f((unsigned short)v1[i]);
        }
    }
#pragma unroll
    for (int i = 0; i < 8; ++i) {
        a[i] += __shfl_xor(a[i], 16);
        a[i] += __shfl_xor(a[i], 32);
    }
    if (seg == 0) {
        float inv = 1.0f / fmaxf((float)deg, 1.0f);
        bf16x8 o;
#pragma unroll
        for (int i = 0; i < 8; ++i) o[i] = (short)f2b(a[i] * inv);
        *(bf16x8*)(Ac + (size_t)node * 256 + dl * 8) = o;
    }
}

// --------------------------------------------------------- fused L1+L2 GEMM
// Per 64-row block:  phase1: h64x256 = relu(Ac @ WT1^T + b1) -> LDS only.
//                    phase2: [y2|t] = h @ WT2^T (+b2), B-frags from L2.
// 4 waves side-by-side in N (wave 64x64, acc 4x4 = 64 AGPR). LDS 41 KB.
#define HSP 264   // h-tile LDS row stride (+8 pad)
__global__ __launch_bounds__(256, 3) void k_fused(
        const ushortT* __restrict__ Ac, const ushortT* __restrict__ WT1,
        const float* __restrict__ b1, const ushortT* __restrict__ WT2,
        const float* __restrict__ b2, ushortT* __restrict__ y2,
        ushortT* __restrict__ t) {
    __shared__ ushortT As[64 * 64];      // 8 KB
    __shared__ ushortT Bs[64 * HSP];     // 33 KB; phase1 B uses [0,16384)
    const int tid = threadIdx.x, l = tid & 63, wid = tid >> 6;
    const int m0 = blockIdx.x * 64;
    const int q = l >> 4, r = l & 15;
    const int swz = (l & 7) ^ ((l >> 3) & 7);

    f32x4 acc[4][4];
#pragma unroll
    for (int i = 0; i < 4; ++i)
#pragma unroll
        for (int j = 0; j < 4; ++j) acc[i][j] = (f32x4){0.f, 0.f, 0.f, 0.f};

    for (int kt = 0; kt < 256; kt += 64) {
#pragma unroll
        for (int i = 0; i < 2; ++i) {             // A: 8 issues of 1 KB
            int flat = wid * 2 + i;
            int row = flat * 8 + (l >> 3);
            llds16(Ac + (size_t)(m0 + row) * 256 + kt + swz * 8, &As[flat * 512]);
        }
#pragma unroll
        for (int i = 0; i < 8; ++i) {             // B: 32 issues of 1 KB
            int flat = wid * 8 + i;
            int row = flat * 8 + (l >> 3);
            llds16(WT1 + (size_t)row * 256 + kt + swz * 8, &Bs[flat * 512]);
        }
        __syncthreads();
#pragma unroll
        for (int ks = 0; ks < 64; ks += 32) {
            bf16x8 af[4], bfr[4];
            const int cs = (((ks >> 3) + q) ^ (r & 7)) * 8;
#pragma unroll
            for (int mt = 0; mt < 4; ++mt)
                af[mt] = *(const bf16x8*)&As[(mt * 16 + r) * 64 + cs];
#pragma unroll
            for (int nt = 0; nt < 4; ++nt)
                bfr[nt] = *(const bf16x8*)&Bs[(wid * 64 + nt * 16 + r) * 64 + cs];
#pragma unroll
            for (int mt = 0; mt < 4; ++mt)
#pragma unroll
                for (int nt = 0; nt < 4; ++nt)
                    acc[mt][nt] = __builtin_amdgcn_mfma_f32_16x16x32_bf16(
                        af[mt], bfr[nt], acc[mt][nt], 0, 0, 0);
        }
        __syncthreads();
    }
    // phase-1 epilogue: +b1, relu, park h-tile in LDS (overwrite Bs)
#pragma unroll
    for (int nt = 0; nt < 4; ++nt) {
        int colb = wid * 64 + nt * 16 + r;
        float bb = b1[colb];
#pragma unroll
        for (int mt = 0; mt < 4; ++mt) {
            int rowb = mt * 16 + q * 4;
#pragma unroll
            for (int j = 0; j < 4; ++j)
                Bs[(rowb + j) * HSP + colb] = f2b(fmaxf(acc[mt][nt][j] + bb, 0.f));
        }
    }
    __syncthreads();

    // phase 2: [y2|t](64x80) = h(LDS) @ WT2^T; wave wid covers col-tiles
    // {wid, wid+4 if <5}; A-frags from LDS, B-frags straight from L2.
    f32x4 acc2[2][4];
#pragma unroll
    for (int i = 0; i < 2; ++i)
#pragma unroll
        for (int j = 0; j < 4; ++j) acc2[i][j] = (f32x4){0.f, 0.f, 0.f, 0.f};
#pragma unroll
    for (int kk = 0; kk < 256; kk += 32) {
        bf16x8 af[4];
#pragma unroll
        for (int mt = 0; mt < 4; ++mt)
            af[mt] = *(const bf16x8*)&Bs[(mt * 16 + r) * HSP + kk + q * 8];
#pragma unroll
        for (int cc = 0; cc < 2; ++cc) {
            int ct = wid + cc * 4;
            if (ct < 5) {
                bf16x8 bq = *(const bf16x8*)(WT2 + (size_t)(ct * 16 + r) * 256 + kk + q * 8);
#pragma unroll
                for (int mt = 0; mt < 4; ++mt)
                    acc2[cc][mt] = __builtin_amdgcn_mfma_f32_16x16x32_bf16(
                        af[mt], bq, acc2[cc][mt], 0, 0, 0);
            }
        }
    }
#pragma unroll
    for (int cc = 0; cc < 2; ++cc) {
        int ct = wid + cc * 4;
        if (ct >= 5) continue;
        int c = ct * 16 + r;
        float bb = (c >= 40) ? b2[c - 40] : 0.f;
#pragma unroll
        for (int mt = 0; mt < 4; ++mt) {
            int row0 = m0 + mt * 16 + q * 4;
#pragma unroll
            for (int j = 0; j < 4; ++j) {
                float v = acc2[cc][mt][j];
                if (c < 40)
                    y2[(size_t)(row0 + j) * 40 + c] = f2b(v);
                else
                    t[(size_t)(row0 + j) * 40 + (c - 40)] = f2b(v + bb);
            }
        }
    }
}

// ------------------------------------------------------- mean aggregation 2
// out = mean_gather(y2 bf16) + t(bf16); col prefetch + 8 loads in flight.
__global__ __launch_bounds__(256) void k_agg2(const int* __restrict__ rp,
                                              const int* __restrict__ bsum,
                                              const int* __restrict__ col,
                                              const ushortT* __restrict__ y2,
                                              const ushortT* __restrict__ t,
                                              float* __restrict__ out) {
    int node = blockIdx.x * 4 + (threadIdx.x >> 6);
    int l = threadIdx.x & 63;
    if (node >= NN) return;
    int seg = l >> 4, dl = l & 15;
    int beg = rp[node] + bsum[node >> 8];
    int end = rp[node + 1] + bsum[(node + 1) >> 8];
    int deg = end - beg;
    bool act = dl < 10;
    float a0 = 0.f, a1 = 0.f, a2 = 0.f, a3 = 0.f;
    for (int base = 0; base < deg; base += 64) {
        int cnt = min(64, deg - base);
        int cv = col[beg + base + min(l, cnt - 1)];
        for (int j = 0; j < cnt; j += 8) {
            int e0 = j + seg, e1 = j + 4 + seg;
            int i0 = __shfl(cv, min(e0, cnt - 1));
            int i1 = __shfl(cv, min(e1, cnt - 1));
            ushort4 v0 = {0, 0, 0, 0}, v1 = {0, 0, 0, 0};
            if (e0 < cnt && act) v0 = *(const ushort4*)(y2 + (size_t)i0 * 40 + dl * 4);
            if (e1 < cnt && act) v1 = *(const ushort4*)(y2 + (size_t)i1 * 40 + dl * 4);
            a0 += b2f(v0.x) + b2f(v1.x);
            a1 += b2f(v0.y) + b2f(v1.y);
            a2 += b2f(v0.z) + b2f(v1.z);
            a3 += b2f(v0.w) + b2f(v1.w);
        }
    }
    a0 += __shfl_xor(a0, 16); a0 += __shfl_xor(a0, 32);
    a1 += __shfl_xor(a1, 16); a1 += __shfl_xor(a1, 32);
    a2 += __shfl_xor(a2, 16); a2 += __shfl_xor(a2, 32);
    a3 += __shfl_xor(a3, 16); a3 += __shfl_xor(a3, 32);
    if (seg == 0 && act) {
        float inv = 1.0f / fmaxf((float)deg, 1.0f);
        size_t o = (size_t)node * 40 + dl * 4;
        ushort4 tv = *(const ushort4*)&t[o];
        float4 ov;
        ov.x = a0 * inv + b2f(tv.x);
        ov.y = a1 * inv + b2f(tv.y);
        ov.z = a2 * inv + b2f(tv.z);
        ov.w = a3 * inv + b2f(tv.w);
        *(float4*)&out[o] = ov;
    }
}

// ------------------------------------------------------------------- launch
extern "C" void kernel_launch(void* const* d_in, const int* in_sizes, int n_in,
                              void* d_out, int out_size, void* d_ws, size_t ws_size,
                              hipStream_t stream) {
    const float* x   = (const float*)d_in[0];
    const int*   ei  = (const int*)d_in[1];
    const int*   src = ei;
    const int*   dst = ei + NE;
    const float* W1l = (const float*)d_in[2];
    const float* b1  = (const float*)d_in[3];
    const float* W1r = (const float*)d_in[4];
    const float* W2l = (const float*)d_in[5];
    const float* b2  = (const float*)d_in[6];
    const float* W2r = (const float*)d_in[7];
    float* out = (float*)d_out;

    size_t off = 0;
    char* base = (char*)d_ws;
    auto alloc = [&](size_t bytes) -> void* {
        void* p = base + off;
        off += (bytes + 255) & ~(size_t)255;
        return p;
    };
    int*     deg8  = (int*)alloc((size_t)8 * NN * 4);
    int*     rp    = (int*)alloc((size_t)(NN + 1) * 4);
    int*     rpp   = (int*)alloc((size_t)8 * NN * 4);
    int*     col   = (int*)alloc((size_t)NE * 4);
    int*     bsum  = (int*)alloc(512 * 4);
    ushortT* Ac    = (ushortT*)alloc((size_t)NNP * 256 * 2);   // [agg|x] bf16
    ushortT* y2    = (ushortT*)alloc((size_t)NNP * 40 * 2);
    ushortT* t     = (ushortT*)alloc((size_t)NNP * 40 * 2);
    ushortT* WT1   = (ushortT*)alloc(256 * 256 * 2);
    ushortT* WT2   = (ushortT*)alloc(80 * 256 * 2);

    k_prep<<<12756, 256, 0, stream>>>(x, W1l, W1r, W2l, W2r, Ac, WT1, WT2,
                                      dst, deg8);
    k_scan1<<<NB1, 256, 0, stream>>>(deg8, rp, rpp, bsum);
    k_scan2<<<1, 512, 0, stream>>>(bsum);
    k_fillcsr<<<256, 256, 0, stream>>>(src, dst, rpp, bsum, col);
    k_agg1<<<(NN + 3) / 4, 256, 0, stream>>>(rp, bsum, col, Ac);
    k_fused<<<NNP / 64, 256, 0, stream>>>(Ac, WT1, b1, WT2, b2, y2, t);
    k_agg2<<<(NN + 3) / 4, 256, 0, stream>>>(rp, bsum, col, y2, t, out);
}

// Round 10
// 326.350 us; speedup vs baseline: 1.5595x; 1.5595x over previous
//
#include <hip/hip_runtime.h>
#include <hip/hip_bf16.h>

// GraphSAGE 2-layer, bf16 MFMA version.
//   L1: h   = relu([agg1|x] @ [W1l;W1r] + b1)   K=256, N=256, bf16 MFMA
//   L2: [y2|t] = h @ [W2l|W2r] (+b2 on t)       K=256, N=80,  bf16 MFMA
//   out = mean_gather(y2) + t
// R10: atomic-free CSR build kept, pass-B fixed: 32 chunks x 16 slices
//      (512 blocks, was 256), and per-block LDS preload of absolute offsets
//      (off[] = bsum+rpp) so the placement loop has NO dependent global
//      gather (R9's 192us fillcsr was 1 block/CU polling rpp at L2 latency).

#define NN   100000
#define NNP  100096          // 782*128 = 1564*64
#define NE   800000
#define NB1  391             // ceil(NN/256)
#define NCHK 32              // edge chunks
#define ECH  25000           // edges per chunk
#define NSLI 16              // node slices
#define NSL  6250            // nodes per slice

typedef unsigned short ushortT;
typedef __attribute__((ext_vector_type(8))) short bf16x8;
typedef __attribute__((ext_vector_type(4))) float f32x4;

__device__ __forceinline__ unsigned short f2b(float f) {
    unsigned u = __float_as_uint(f);
    return (unsigned short)((u + 0x7fffu + ((u >> 16) & 1u)) >> 16);
}
__device__ __forceinline__ float b2f(unsigned short v) {
    return __uint_as_float(((unsigned)v) << 16);
}
__device__ __forceinline__ void llds16(const unsigned short* g, unsigned short* s) {
    __builtin_amdgcn_global_load_lds(
        (const __attribute__((address_space(1))) void*)g,
        (__attribute__((address_space(3))) void*)s, 16, 0, 0);
}

// --------------------------------------------- prep + histogram (pass A)
// blocks [0,12500): x->bf16 cast + weight transpose/cast
// blocks [12500,13012): block (c,s) LDS-counts chunk-c edges landing in
//                       slice s -> deg32[c][node] (no global atomics)
__global__ __launch_bounds__(256) void k_prep(
        const float* __restrict__ x,
        const float* __restrict__ W1l, const float* __restrict__ W1r,
        const float* __restrict__ W2l, const float* __restrict__ W2r,
        ushortT* __restrict__ Ac, ushortT* __restrict__ WT1,
        ushortT* __restrict__ WT2,
        const int* __restrict__ dst, int* __restrict__ deg32) {
    __shared__ int hist[NSL];
    int bid = blockIdx.x;
    if (bid < 12500) {
        int t = bid * 256 + threadIdx.x;          // [0, NN*32)
        int row = t >> 5, c4 = t & 31;
        float4 v = *(const float4*)&x[(size_t)row * 128 + c4 * 4];
        ushortT* p = Ac + (size_t)row * 256 + 128 + c4 * 4;
        p[0] = f2b(v.x); p[1] = f2b(v.y); p[2] = f2b(v.z); p[3] = f2b(v.w);

        if (t < 65536) {                          // WT1 [256n][256k]
            int n = t >> 8, k = t & 255;
            float w = (k < 128) ? W1l[(size_t)k * 256 + n]
                                : W1r[(size_t)(k - 128) * 256 + n];
            WT1[t] = f2b(w);
        } else if (t < 65536 + 20480) {           // WT2 [80n][256k]
            int j = t - 65536;
            int n = j >> 8, k = j & 255;
            float w = (n < 40) ? W2l[(size_t)k * 40 + n]
                               : W2r[(size_t)k * 40 + (n - 40)];
            WT2[j] = f2b(w);
        }
    } else {
        int idx = bid - 12500;                    // [0,512)
        int s = idx & (NSLI - 1), c = idx >> 4;
        for (int i = threadIdx.x; i < NSL; i += 256) hist[i] = 0;
        __syncthreads();
        int e0 = c * ECH, lo = s * NSL;
        for (int i = threadIdx.x; i < ECH; i += 256) {
            unsigned dd = (unsigned)(dst[e0 + i] - lo);
            if (dd < (unsigned)NSL) atomicAdd(&hist[dd], 1);
        }
        __syncthreads();
        for (int i = threadIdx.x; i < NSL; i += 256)
            deg32[c * NN + lo + i] = hist[i];
    }
}

// ------------------------------------------- scan over summed chunk degs
// rp[i] = block-local exclusive prefix of deg_tot; rpp[c][i] = rp[i] +
// sum of chunks < c (fill's per-chunk base). bsum = per-block totals.
__global__ __launch_bounds__(256) void k_scan1(const int* __restrict__ deg32,
                                               int* __restrict__ rp,
                                               int* __restrict__ rpp,
                                               int* __restrict__ bsum) {
    __shared__ int s[256];
    int t = threadIdx.x;
    int i = blockIdx.x * 256 + t;
    int d32[NCHK];
    int v = 0;
#pragma unroll
    for (int r = 0; r < NCHK; ++r) {
        d32[r] = (i < NN) ? deg32[r * NN + i] : 0;
        v += d32[r];
    }
    s[t] = v;
    __syncthreads();
    for (int off = 1; off < 256; off <<= 1) {
        int add = (t >= off) ? s[t - off] : 0;
        __syncthreads();
        s[t] += add;
        __syncthreads();
    }
    int ex = s[t] - v;
    if (i <= NN) rp[i] = ex;                      // i==NN: v=0 -> exclusive end
    if (i < NN) {
        int run = ex;
#pragma unroll
        for (int r = 0; r < NCHK; ++r) {
            rpp[r * NN + i] = run;
            run += d32[r];
        }
    }
    if (t == 255) bsum[blockIdx.x] = s[255];
}

__global__ __launch_bounds__(512) void k_scan2(int* __restrict__ bsum) {
    __shared__ int s[512];
    int t = threadIdx.x;
    int v = (t < NB1) ? bsum[t] : 0;
    s[t] = v;
    __syncthreads();
    for (int off = 1; off < 512; off <<= 1) {
        int add = (t >= off) ? s[t - off] : 0;
        __syncthreads();
        s[t] += add;
        __syncthreads();
    }
    if (t < NB1) bsum[t] = s[t] - v;              // exclusive block offsets
}

// --------------------------------------------------- CSR fill (pass B)
// block (c,s): preload ABSOLUTE offsets off[i]=bsum+rpp (coalesced, LDS),
// then scan chunk c; matching edges take k=ldsAtomicAdd and store col[k].
// Inner loop: only coalesced streaming loads + LDS atomic + blind store.
// bid = c*16+s -> bid%8 == s%8: one XCD owns each slice's col region.
__global__ __launch_bounds__(256) void k_fillB(const int* __restrict__ src,
                                               const int* __restrict__ dst,
                                               const int* __restrict__ rpp,
                                               const int* __restrict__ bsum,
                                               int* __restrict__ col) {
    __shared__ int off[NSL];
    int s = blockIdx.x & (NSLI - 1), c = blockIdx.x >> 4;
    int lo = s * NSL;
    for (int i = threadIdx.x; i < NSL; i += 256)
        off[i] = bsum[(lo + i) >> 8] + rpp[c * NN + lo + i];
    __syncthreads();
    int e0 = c * ECH;
    for (int i = threadIdx.x; i < ECH; i += 256) {
        int e = e0 + i;
        int d = dst[e];
        int sv = src[e];
        unsigned dd = (unsigned)(d - lo);
        if (dd < (unsigned)NSL) {
            int k = atomicAdd(&off[dd], 1);       // LDS atomic
            col[k] = sv;
        }
    }
}

// ------------------------------------------------------- mean aggregation 1
// gather bf16 x rows (A_cat[:,128:]), write bf16 mean to A_cat[:,0:128].
// One wave per node; col prefetch + __shfl bcast; 8 row-loads in flight.
__global__ __launch_bounds__(256) void k_agg1(const int* __restrict__ rp,
                                              const int* __restrict__ bsum,
                                              const int* __restrict__ col,
                                              ushortT* __restrict__ Ac) {
    int node = blockIdx.x * 4 + (threadIdx.x >> 6);
    int l = threadIdx.x & 63;
    if (node >= NN) return;
    int seg = l >> 4, dl = l & 15;
    int beg = rp[node] + bsum[node >> 8];
    int end = rp[node + 1] + bsum[(node + 1) >> 8];
    int deg = end - beg;
    float a[8] = {0.f, 0.f, 0.f, 0.f, 0.f, 0.f, 0.f, 0.f};
    for (int base = 0; base < deg; base += 64) {
        int cnt = min(64, deg - base);
        int cv = col[beg + base + min(l, cnt - 1)];
        for (int j = 0; j < cnt; j += 8) {
            int e0 = j + seg, e1 = j + 4 + seg;
            int i0 = __shfl(cv, min(e0, cnt - 1));
            int i1 = __shfl(cv, min(e1, cnt - 1));
            bf16x8 v0 = {0, 0, 0, 0, 0, 0, 0, 0};
            bf16x8 v1 = {0, 0, 0, 0, 0, 0, 0, 0};
            if (e0 < cnt) v0 = *(const bf16x8*)(Ac + (size_t)i0 * 256 + 128 + dl * 8);
            if (e1 < cnt) v1 = *(const bf16x8*)(Ac + (size_t)i1 * 256 + 128 + dl * 8);
#pragma unroll
            for (int i = 0; i < 8; ++i)
                a[i] += b2f((unsigned short)v0[i]) + b2f((unsigned short)v1[i]);
        }
    }
#pragma unroll
    for (int i = 0; i < 8; ++i) {
        a[i] += __shfl_xor(a[i], 16);
        a[i] += __shfl_xor(a[i], 32);
    }
    if (seg == 0) {
        float inv = 1.0f / fmaxf((float)deg, 1.0f);
        bf16x8 o;
#pragma unroll
        for (int i = 0; i < 8; ++i) o[i] = (short)f2b(a[i] * inv);
        *(bf16x8*)(Ac + (size_t)node * 256 + dl * 8) = o;
    }
}

// --------------------------------------------------------- fused L1+L2 GEMM
// Per 64-row block:  phase1: h64x256 = relu(Ac @ WT1^T + b1) -> LDS only.
//                    phase2: [y2|t] = h @ WT2^T (+b2), B-frags from L2.
// 4 waves side-by-side in N (wave 64x64, acc 4x4 = 64 AGPR). LDS 41 KB.
#define HSP 264   // h-tile LDS row stride (+8 pad)
__global__ __launch_bounds__(256, 3) void k_fused(
        const ushortT* __restrict__ Ac, const ushortT* __restrict__ WT1,
        const float* __restrict__ b1, const ushortT* __restrict__ WT2,
        const float* __restrict__ b2, ushortT* __restrict__ y2,
        ushortT* __restrict__ t) {
    __shared__ ushortT As[64 * 64];      // 8 KB
    __shared__ ushortT Bs[64 * HSP];     // 33 KB; phase1 B uses [0,16384)
    const int tid = threadIdx.x, l = tid & 63, wid = tid >> 6;
    const int m0 = blockIdx.x * 64;
    const int q = l >> 4, r = l & 15;
    const int swz = (l & 7) ^ ((l >> 3) & 7);

    f32x4 acc[4][4];
#pragma unroll
    for (int i = 0; i < 4; ++i)
#pragma unroll
        for (int j = 0; j < 4; ++j) acc[i][j] = (f32x4){0.f, 0.f, 0.f, 0.f};

    for (int kt = 0; kt < 256; kt += 64) {
#pragma unroll
        for (int i = 0; i < 2; ++i) {             // A: 8 issues of 1 KB
            int flat = wid * 2 + i;
            int row = flat * 8 + (l >> 3);
            llds16(Ac + (size_t)(m0 + row) * 256 + kt + swz * 8, &As[flat * 512]);
        }
#pragma unroll
        for (int i = 0; i < 8; ++i) {             // B: 32 issues of 1 KB
            int flat = wid * 8 + i;
            int row = flat * 8 + (l >> 3);
            llds16(WT1 + (size_t)row * 256 + kt + swz * 8, &Bs[flat * 512]);
        }
        __syncthreads();
#pragma unroll
        for (int ks = 0; ks < 64; ks += 32) {
            bf16x8 af[4], bfr[4];
            const int cs = (((ks >> 3) + q) ^ (r & 7)) * 8;
#pragma unroll
            for (int mt = 0; mt < 4; ++mt)
                af[mt] = *(const bf16x8*)&As[(mt * 16 + r) * 64 + cs];
#pragma unroll
            for (int nt = 0; nt < 4; ++nt)
                bfr[nt] = *(const bf16x8*)&Bs[(wid * 64 + nt * 16 + r) * 64 + cs];
#pragma unroll
            for (int mt = 0; mt < 4; ++mt)
#pragma unroll
                for (int nt = 0; nt < 4; ++nt)
                    acc[mt][nt] = __builtin_amdgcn_mfma_f32_16x16x32_bf16(
                        af[mt], bfr[nt], acc[mt][nt], 0, 0, 0);
        }
        __syncthreads();
    }
    // phase-1 epilogue: +b1, relu, park h-tile in LDS (overwrite Bs)
#pragma unroll
    for (int nt = 0; nt < 4; ++nt) {
        int colb = wid * 64 + nt * 16 + r;
        float bb = b1[colb];
#pragma unroll
        for (int mt = 0; mt < 4; ++mt) {
            int rowb = mt * 16 + q * 4;
#pragma unroll
            for (int j = 0; j < 4; ++j)
                Bs[(rowb + j) * HSP + colb] = f2b(fmaxf(acc[mt][nt][j] + bb, 0.f));
        }
    }
    __syncthreads();

    // phase 2: [y2|t](64x80) = h(LDS) @ WT2^T; wave wid covers col-tiles
    // {wid, wid+4 if <5}; A-frags from LDS, B-frags straight from L2.
    f32x4 acc2[2][4];
#pragma unroll
    for (int i = 0; i < 2; ++i)
#pragma unroll
        for (int j = 0; j < 4; ++j) acc2[i][j] = (f32x4){0.f, 0.f, 0.f, 0.f};
#pragma unroll
    for (int kk = 0; kk < 256; kk += 32) {
        bf16x8 af[4];
#pragma unroll
        for (int mt = 0; mt < 4; ++mt)
            af[mt] = *(const bf16x8*)&Bs[(mt * 16 + r) * HSP + kk + q * 8];
#pragma unroll
        for (int cc = 0; cc < 2; ++cc) {
            int ct = wid + cc * 4;
            if (ct < 5) {
                bf16x8 bq = *(const bf16x8*)(WT2 + (size_t)(ct * 16 + r) * 256 + kk + q * 8);
#pragma unroll
                for (int mt = 0; mt < 4; ++mt)
                    acc2[cc][mt] = __builtin_amdgcn_mfma_f32_16x16x32_bf16(
                        af[mt], bq, acc2[cc][mt], 0, 0, 0);
            }
        }
    }
#pragma unroll
    for (int cc = 0; cc < 2; ++cc) {
        int ct = wid + cc * 4;
        if (ct >= 5) continue;
        int c = ct * 16 + r;
        float bb = (c >= 40) ? b2[c - 40] : 0.f;
#pragma unroll
        for (int mt = 0; mt < 4; ++mt) {
            int row0 = m0 + mt * 16 + q * 4;
#pragma unroll
            for (int j = 0; j < 4; ++j) {
                float v = acc2[cc][mt][j];
                if (c < 40)
                    y2[(size_t)(row0 + j) * 40 + c] = f2b(v);
                else
                    t[(size_t)(row0 + j) * 40 + (c - 40)] = f2b(v + bb);
            }
        }
    }
}

// ------------------------------------------------------- mean aggregation 2
// out = mean_gather(y2 bf16) + t(bf16); col prefetch + 8 loads in flight.
__global__ __launch_bounds__(256) void k_agg2(const int* __restrict__ rp,
                                              const int* __restrict__ bsum,
                                              const int* __restrict__ col,
                                              const ushortT* __restrict__ y2,
                                              const ushortT* __restrict__ t,
                                              float* __restrict__ out) {
    int node = blockIdx.x * 4 + (threadIdx.x >> 6);
    int l = threadIdx.x & 63;
    if (node >= NN) return;
    int seg = l >> 4, dl = l & 15;
    int beg = rp[node] + bsum[node >> 8];
    int end = rp[node + 1] + bsum[(node + 1) >> 8];
    int deg = end - beg;
    bool act = dl < 10;
    float a0 = 0.f, a1 = 0.f, a2 = 0.f, a3 = 0.f;
    for (int base = 0; base < deg; base += 64) {
        int cnt = min(64, deg - base);
        int cv = col[beg + base + min(l, cnt - 1)];
        for (int j = 0; j < cnt; j += 8) {
            int e0 = j + seg, e1 = j + 4 + seg;
            int i0 = __shfl(cv, min(e0, cnt - 1));
            int i1 = __shfl(cv, min(e1, cnt - 1));
            ushort4 v0 = {0, 0, 0, 0}, v1 = {0, 0, 0, 0};
            if (e0 < cnt && act) v0 = *(const ushort4*)(y2 + (size_t)i0 * 40 + dl * 4);
            if (e1 < cnt && act) v1 = *(const ushort4*)(y2 + (size_t)i1 * 40 + dl * 4);
            a0 += b2f(v0.x) + b2f(v1.x);
            a1 += b2f(v0.y) + b2f(v1.y);
            a2 += b2f(v0.z) + b2f(v1.z);
            a3 += b2f(v0.w) + b2f(v1.w);
        }
    }
    a0 += __shfl_xor(a0, 16); a0 += __shfl_xor(a0, 32);
    a1 += __shfl_xor(a1, 16); a1 += __shfl_xor(a1, 32);
    a2 += __shfl_xor(a2, 16); a2 += __shfl_xor(a2, 32);
    a3 += __shfl_xor(a3, 16); a3 += __shfl_xor(a3, 32);
    if (seg == 0 && act) {
        float inv = 1.0f / fmaxf((float)deg, 1.0f);
        size_t o = (size_t)node * 40 + dl * 4;
        ushort4 tv = *(const ushort4*)&t[o];
        float4 ov;
        ov.x = a0 * inv + b2f(tv.x);
        ov.y = a1 * inv + b2f(tv.y);
        ov.z = a2 * inv + b2f(tv.z);
        ov.w = a3 * inv + b2f(tv.w);
        *(float4*)&out[o] = ov;
    }
}

// ------------------------------------------------------------------- launch
extern "C" void kernel_launch(void* const* d_in, const int* in_sizes, int n_in,
                              void* d_out, int out_size, void* d_ws, size_t ws_size,
                              hipStream_t stream) {
    const float* x   = (const float*)d_in[0];
    const int*   ei  = (const int*)d_in[1];
    const int*   src = ei;
    const int*   dst = ei + NE;
    const float* W1l = (const float*)d_in[2];
    const float* b1  = (const float*)d_in[3];
    const float* W1r = (const float*)d_in[4];
    const float* W2l = (const float*)d_in[5];
    const float* b2  = (const float*)d_in[6];
    const float* W2r = (const float*)d_in[7];
    float* out = (float*)d_out;

    size_t off = 0;
    char* base = (char*)d_ws;
    auto alloc = [&](size_t bytes) -> void* {
        void* p = base + off;
        off += (bytes + 255) & ~(size_t)255;
        return p;
    };
    int*     deg32 = (int*)alloc((size_t)NCHK * NN * 4);
    int*     rp    = (int*)alloc((size_t)(NN + 1) * 4);
    int*     rpp   = (int*)alloc((size_t)NCHK * NN * 4);
    int*     col   = (int*)alloc((size_t)NE * 4);
    int*     bsum  = (int*)alloc(512 * 4);
    ushortT* Ac    = (ushortT*)alloc((size_t)NNP * 256 * 2);   // [agg|x] bf16
    ushortT* y2    = (ushortT*)alloc((size_t)NNP * 40 * 2);
    ushortT* t     = (ushortT*)alloc((size_t)NNP * 40 * 2);
    ushortT* WT1   = (ushortT*)alloc(256 * 256 * 2);
    ushortT* WT2   = (ushortT*)alloc(80 * 256 * 2);

    k_prep<<<12500 + NCHK * NSLI, 256, 0, stream>>>(x, W1l, W1r, W2l, W2r,
                                                    Ac, WT1, WT2, dst, deg32);
    k_scan1<<<NB1, 256, 0, stream>>>(deg32, rp, rpp, bsum);
    k_scan2<<<1, 512, 0, stream>>>(bsum);
    k_fillB<<<NCHK * NSLI, 256, 0, stream>>>(src, dst, rpp, bsum, col);
    k_agg1<<<(NN + 3) / 4, 256, 0, stream>>>(rp, bsum, col, Ac);
    k_fused<<<NNP / 64, 256, 0, stream>>>(Ac, WT1, b1, WT2, b2, y2, t);
    k_agg2<<<(NN + 3) / 4, 256, 0, stream>>>(rp, bsum, col, y2, t, out);
}

// Round 11
// 269.255 us; speedup vs baseline: 1.8901x; 1.2120x over previous
//
#include <hip/hip_runtime.h>
#include <hip/hip_bf16.h>

// GraphSAGE 2-layer, bf16 MFMA version.
//   L1: h   = relu([agg1|x] @ [W1l;W1r] + b1)   K=256, N=256, bf16 MFMA
//   L2: [y2|t] = h @ [W2l|W2r] (+b2 on t)       K=256, N=80,  bf16 MFMA
//   out = mean_gather(y2) + t
// R11: MLP fixes. fillB/prep-hist: 4-batched loads issued before the LDS
//      atomic (R10's loop ran ~660cyc/iter = un-pipelined). agg1/agg2:
//      edge unroll 2->4 (16 row-loads in flight). Structure unchanged.

#define NN   100000
#define NNP  100096          // 782*128 = 1564*64
#define NE   800000
#define NB1  391             // ceil(NN/256)
#define NCHK 32              // edge chunks
#define ECH  25000           // edges per chunk
#define NSLI 16              // node slices
#define NSL  6250            // nodes per slice

typedef unsigned short ushortT;
typedef __attribute__((ext_vector_type(8))) short bf16x8;
typedef __attribute__((ext_vector_type(4))) float f32x4;

__device__ __forceinline__ unsigned short f2b(float f) {
    unsigned u = __float_as_uint(f);
    return (unsigned short)((u + 0x7fffu + ((u >> 16) & 1u)) >> 16);
}
__device__ __forceinline__ float b2f(unsigned short v) {
    return __uint_as_float(((unsigned)v) << 16);
}
__device__ __forceinline__ void llds16(const unsigned short* g, unsigned short* s) {
    __builtin_amdgcn_global_load_lds(
        (const __attribute__((address_space(1))) void*)g,
        (__attribute__((address_space(3))) void*)s, 16, 0, 0);
}

// --------------------------------------------- prep + histogram (pass A)
// blocks [0,12500): x->bf16 cast + weight transpose/cast
// blocks [12500,13012): block (c,s) LDS-counts chunk-c edges landing in
//                       slice s -> deg32[c][node]; loads 4-batched for MLP
__global__ __launch_bounds__(256) void k_prep(
        const float* __restrict__ x,
        const float* __restrict__ W1l, const float* __restrict__ W1r,
        const float* __restrict__ W2l, const float* __restrict__ W2r,
        ushortT* __restrict__ Ac, ushortT* __restrict__ WT1,
        ushortT* __restrict__ WT2,
        const int* __restrict__ dst, int* __restrict__ deg32) {
    __shared__ int hist[NSL];
    int bid = blockIdx.x;
    if (bid < 12500) {
        int t = bid * 256 + threadIdx.x;          // [0, NN*32)
        int row = t >> 5, c4 = t & 31;
        float4 v = *(const float4*)&x[(size_t)row * 128 + c4 * 4];
        ushortT* p = Ac + (size_t)row * 256 + 128 + c4 * 4;
        p[0] = f2b(v.x); p[1] = f2b(v.y); p[2] = f2b(v.z); p[3] = f2b(v.w);

        if (t < 65536) {                          // WT1 [256n][256k]
            int n = t >> 8, k = t & 255;
            float w = (k < 128) ? W1l[(size_t)k * 256 + n]
                                : W1r[(size_t)(k - 128) * 256 + n];
            WT1[t] = f2b(w);
        } else if (t < 65536 + 20480) {           // WT2 [80n][256k]
            int j = t - 65536;
            int n = j >> 8, k = j & 255;
            float w = (n < 40) ? W2l[(size_t)k * 40 + n]
                               : W2r[(size_t)k * 40 + (n - 40)];
            WT2[j] = f2b(w);
        }
    } else {
        int idx = bid - 12500;                    // [0,512)
        int s = idx & (NSLI - 1), c = idx >> 4;
        for (int i = threadIdx.x; i < NSL; i += 256) hist[i] = 0;
        __syncthreads();
        int e0 = c * ECH, lo = s * NSL;
        for (int i = threadIdx.x; i < ECH; i += 1024) {
            int d[4];
            bool m[4];
#pragma unroll
            for (int u = 0; u < 4; ++u) {
                int ii = i + u * 256;
                m[u] = ii < ECH;
                d[u] = dst[e0 + (m[u] ? ii : 0)];
            }
#pragma unroll
            for (int u = 0; u < 4; ++u) {
                unsigned dd = (unsigned)(d[u] - lo);
                if (m[u] && dd < (unsigned)NSL) atomicAdd(&hist[dd], 1);
            }
        }
        __syncthreads();
        for (int i = threadIdx.x; i < NSL; i += 256)
            deg32[c * NN + lo + i] = hist[i];
    }
}

// ------------------------------------------- scan over summed chunk degs
__global__ __launch_bounds__(256) void k_scan1(const int* __restrict__ deg32,
                                               int* __restrict__ rp,
                                               int* __restrict__ rpp,
                                               int* __restrict__ bsum) {
    __shared__ int s[256];
    int t = threadIdx.x;
    int i = blockIdx.x * 256 + t;
    int d32[NCHK];
    int v = 0;
#pragma unroll
    for (int r = 0; r < NCHK; ++r) {
        d32[r] = (i < NN) ? deg32[r * NN + i] : 0;
        v += d32[r];
    }
    s[t] = v;
    __syncthreads();
    for (int off = 1; off < 256; off <<= 1) {
        int add = (t >= off) ? s[t - off] : 0;
        __syncthreads();
        s[t] += add;
        __syncthreads();
    }
    int ex = s[t] - v;
    if (i <= NN) rp[i] = ex;                      // i==NN: v=0 -> exclusive end
    if (i < NN) {
        int run = ex;
#pragma unroll
        for (int r = 0; r < NCHK; ++r) {
            rpp[r * NN + i] = run;
            run += d32[r];
        }
    }
    if (t == 255) bsum[blockIdx.x] = s[255];
}

__global__ __launch_bounds__(512) void k_scan2(int* __restrict__ bsum) {
    __shared__ int s[512];
    int t = threadIdx.x;
    int v = (t < NB1) ? bsum[t] : 0;
    s[t] = v;
    __syncthreads();
    for (int off = 1; off < 512; off <<= 1) {
        int add = (t >= off) ? s[t - off] : 0;
        __syncthreads();
        s[t] += add;
        __syncthreads();
    }
    if (t < NB1) bsum[t] = s[t] - v;              // exclusive block offsets
}

// --------------------------------------------------- CSR fill (pass B)
// block (c,s): preload ABSOLUTE offsets off[i]=bsum+rpp (coalesced, LDS),
// then scan chunk c with 4-batched dst/src loads (8 loads in flight before
// any LDS atomic / scatter store).
__global__ __launch_bounds__(256) void k_fillB(const int* __restrict__ src,
                                               const int* __restrict__ dst,
                                               const int* __restrict__ rpp,
                                               const int* __restrict__ bsum,
                                               int* __restrict__ col) {
    __shared__ int off[NSL];
    int s = blockIdx.x & (NSLI - 1), c = blockIdx.x >> 4;
    int lo = s * NSL;
    for (int i = threadIdx.x; i < NSL; i += 256)
        off[i] = bsum[(lo + i) >> 8] + rpp[c * NN + lo + i];
    __syncthreads();
    int e0 = c * ECH;
    for (int i = threadIdx.x; i < ECH; i += 1024) {
        int d[4], sv[4];
        bool m[4];
#pragma unroll
        for (int u = 0; u < 4; ++u) {
            int ii = i + u * 256;
            m[u] = ii < ECH;
            int e = e0 + (m[u] ? ii : 0);
            d[u] = dst[e];
            sv[u] = src[e];
        }
#pragma unroll
        for (int u = 0; u < 4; ++u) {
            unsigned dd = (unsigned)(d[u] - lo);
            if (m[u] && dd < (unsigned)NSL) {
                int k = atomicAdd(&off[dd], 1);   // LDS atomic
                col[k] = sv[u];
            }
        }
    }
}

// ------------------------------------------------------- mean aggregation 1
// gather bf16 x rows (A_cat[:,128:]), write bf16 mean to A_cat[:,0:128].
// One wave per node; col prefetch + __shfl bcast; 16 row-loads in flight.
__global__ __launch_bounds__(256) void k_agg1(const int* __restrict__ rp,
                                              const int* __restrict__ bsum,
                                              const int* __restrict__ col,
                                              ushortT* __restrict__ Ac) {
    int node = blockIdx.x * 4 + (threadIdx.x >> 6);
    int l = threadIdx.x & 63;
    if (node >= NN) return;
    int seg = l >> 4, dl = l & 15;
    int beg = rp[node] + bsum[node >> 8];
    int end = rp[node + 1] + bsum[(node + 1) >> 8];
    int deg = end - beg;
    float a[8] = {0.f, 0.f, 0.f, 0.f, 0.f, 0.f, 0.f, 0.f};
    for (int base = 0; base < deg; base += 64) {
        int cnt = min(64, deg - base);
        int cv = col[beg + base + min(l, cnt - 1)];
        for (int j = 0; j < cnt; j += 16) {
            int e[4], idx[4];
            bf16x8 v[4];
#pragma unroll
            for (int u = 0; u < 4; ++u) {
                e[u] = j + u * 4 + seg;
                idx[u] = __shfl(cv, min(e[u], cnt - 1));
            }
#pragma unroll
            for (int u = 0; u < 4; ++u) {
                v[u] = (bf16x8){0, 0, 0, 0, 0, 0, 0, 0};
                if (e[u] < cnt)
                    v[u] = *(const bf16x8*)(Ac + (size_t)idx[u] * 256 + 128 + dl * 8);
            }
#pragma unroll
            for (int u = 0; u < 4; ++u)
#pragma unroll
                for (int i = 0; i < 8; ++i)
                    a[i] += b2f((unsigned short)v[u][i]);
        }
    }
#pragma unroll
    for (int i = 0; i < 8; ++i) {
        a[i] += __shfl_xor(a[i], 16);
        a[i] += __shfl_xor(a[i], 32);
    }
    if (seg == 0) {
        float inv = 1.0f / fmaxf((float)deg, 1.0f);
        bf16x8 o;
#pragma unroll
        for (int i = 0; i < 8; ++i) o[i] = (short)f2b(a[i] * inv);
        *(bf16x8*)(Ac + (size_t)node * 256 + dl * 8) = o;
    }
}

// --------------------------------------------------------- fused L1+L2 GEMM
// Per 64-row block:  phase1: h64x256 = relu(Ac @ WT1^T + b1) -> LDS only.
//                    phase2: [y2|t] = h @ WT2^T (+b2), B-frags from L2.
// 4 waves side-by-side in N (wave 64x64, acc 4x4 = 64 AGPR). LDS 41 KB.
#define HSP 264   // h-tile LDS row stride (+8 pad)
__global__ __launch_bounds__(256, 3) void k_fused(
        const ushortT* __restrict__ Ac, const ushortT* __restrict__ WT1,
        const float* __restrict__ b1, const ushortT* __restrict__ WT2,
        const float* __restrict__ b2, ushortT* __restrict__ y2,
        ushortT* __restrict__ t) {
    __shared__ ushortT As[64 * 64];      // 8 KB
    __shared__ ushortT Bs[64 * HSP];     // 33 KB; phase1 B uses [0,16384)
    const int tid = threadIdx.x, l = tid & 63, wid = tid >> 6;
    const int m0 = blockIdx.x * 64;
    const int q = l >> 4, r = l & 15;
    const int swz = (l & 7) ^ ((l >> 3) & 7);

    f32x4 acc[4][4];
#pragma unroll
    for (int i = 0; i < 4; ++i)
#pragma unroll
        for (int j = 0; j < 4; ++j) acc[i][j] = (f32x4){0.f, 0.f, 0.f, 0.f};

    for (int kt = 0; kt < 256; kt += 64) {
#pragma unroll
        for (int i = 0; i < 2; ++i) {             // A: 8 issues of 1 KB
            int flat = wid * 2 + i;
            int row = flat * 8 + (l >> 3);
            llds16(Ac + (size_t)(m0 + row) * 256 + kt + swz * 8, &As[flat * 512]);
        }
#pragma unroll
        for (int i = 0; i < 8; ++i) {             // B: 32 issues of 1 KB
            int flat = wid * 8 + i;
            int row = flat * 8 + (l >> 3);
            llds16(WT1 + (size_t)row * 256 + kt + swz * 8, &Bs[flat * 512]);
        }
        __syncthreads();
#pragma unroll
        for (int ks = 0; ks < 64; ks += 32) {
            bf16x8 af[4], bfr[4];
            const int cs = (((ks >> 3) + q) ^ (r & 7)) * 8;
#pragma unroll
            for (int mt = 0; mt < 4; ++mt)
                af[mt] = *(const bf16x8*)&As[(mt * 16 + r) * 64 + cs];
#pragma unroll
            for (int nt = 0; nt < 4; ++nt)
                bfr[nt] = *(const bf16x8*)&Bs[(wid * 64 + nt * 16 + r) * 64 + cs];
#pragma unroll
            for (int mt = 0; mt < 4; ++mt)
#pragma unroll
                for (int nt = 0; nt < 4; ++nt)
                    acc[mt][nt] = __builtin_amdgcn_mfma_f32_16x16x32_bf16(
                        af[mt], bfr[nt], acc[mt][nt], 0, 0, 0);
        }
        __syncthreads();
    }
    // phase-1 epilogue: +b1, relu, park h-tile in LDS (overwrite Bs)
#pragma unroll
    for (int nt = 0; nt < 4; ++nt) {
        int colb = wid * 64 + nt * 16 + r;
        float bb = b1[colb];
#pragma unroll
        for (int mt = 0; mt < 4; ++mt) {
            int rowb = mt * 16 + q * 4;
#pragma unroll
            for (int j = 0; j < 4; ++j)
                Bs[(rowb + j) * HSP + colb] = f2b(fmaxf(acc[mt][nt][j] + bb, 0.f));
        }
    }
    __syncthreads();

    // phase 2: [y2|t](64x80) = h(LDS) @ WT2^T; wave wid covers col-tiles
    // {wid, wid+4 if <5}; A-frags from LDS, B-frags straight from L2.
    f32x4 acc2[2][4];
#pragma unroll
    for (int i = 0; i < 2; ++i)
#pragma unroll
        for (int j = 0; j < 4; ++j) acc2[i][j] = (f32x4){0.f, 0.f, 0.f, 0.f};
#pragma unroll
    for (int kk = 0; kk < 256; kk += 32) {
        bf16x8 af[4];
#pragma unroll
        for (int mt = 0; mt < 4; ++mt)
            af[mt] = *(const bf16x8*)&Bs[(mt * 16 + r) * HSP + kk + q * 8];
#pragma unroll
        for (int cc = 0; cc < 2; ++cc) {
            int ct = wid + cc * 4;
            if (ct < 5) {
                bf16x8 bq = *(const bf16x8*)(WT2 + (size_t)(ct * 16 + r) * 256 + kk + q * 8);
#pragma unroll
                for (int mt = 0; mt < 4; ++mt)
                    acc2[cc][mt] = __builtin_amdgcn_mfma_f32_16x16x32_bf16(
                        af[mt], bq, acc2[cc][mt], 0, 0, 0);
            }
        }
    }
#pragma unroll
    for (int cc = 0; cc < 2; ++cc) {
        int ct = wid + cc * 4;
        if (ct >= 5) continue;
        int c = ct * 16 + r;
        float bb = (c >= 40) ? b2[c - 40] : 0.f;
#pragma unroll
        for (int mt = 0; mt < 4; ++mt) {
            int row0 = m0 + mt * 16 + q * 4;
#pragma unroll
            for (int j = 0; j < 4; ++j) {
                float v = acc2[cc][mt][j];
                if (c < 40)
                    y2[(size_t)(row0 + j) * 40 + c] = f2b(v);
                else
                    t[(size_t)(row0 + j) * 40 + (c - 40)] = f2b(v + bb);
            }
        }
    }
}

// ------------------------------------------------------- mean aggregation 2
// out = mean_gather(y2 bf16) + t(bf16); 16 loads in flight.
__global__ __launch_bounds__(256) void k_agg2(const int* __restrict__ rp,
                                              const int* __restrict__ bsum,
                                              const int* __restrict__ col,
                                              const ushortT* __restrict__ y2,
                                              const ushortT* __restrict__ t,
                                              float* __restrict__ out) {
    int node = blockIdx.x * 4 + (threadIdx.x >> 6);
    int l = threadIdx.x & 63;
    if (node >= NN) return;
    int seg = l >> 4, dl = l & 15;
    int beg = rp[node] + bsum[node >> 8];
    int end = rp[node + 1] + bsum[(node + 1) >> 8];
    int deg = end - beg;
    bool act = dl < 10;
    float a0 = 0.f, a1 = 0.f, a2 = 0.f, a3 = 0.f;
    for (int base = 0; base < deg; base += 64) {
        int cnt = min(64, deg - base);
        int cv = col[beg + base + min(l, cnt - 1)];
        for (int j = 0; j < cnt; j += 16) {
            int e[4], idx[4];
            ushort4 v[4];
#pragma unroll
            for (int u = 0; u < 4; ++u) {
                e[u] = j + u * 4 + seg;
                idx[u] = __shfl(cv, min(e[u], cnt - 1));
            }
#pragma unroll
            for (int u = 0; u < 4; ++u) {
                v[u] = (ushort4){0, 0, 0, 0};
                if (e[u] < cnt && act)
                    v[u] = *(const ushort4*)(y2 + (size_t)idx[u] * 40 + dl * 4);
            }
#pragma unroll
            for (int u = 0; u < 4; ++u) {
                a0 += b2f(v[u].x);
                a1 += b2f(v[u].y);
                a2 += b2f(v[u].z);
                a3 += b2f(v[u].w);
            }
        }
    }
    a0 += __shfl_xor(a0, 16); a0 += __shfl_xor(a0, 32);
    a1 += __shfl_xor(a1, 16); a1 += __shfl_xor(a1, 32);
    a2 += __shfl_xor(a2, 16); a2 += __shfl_xor(a2, 32);
    a3 += __shfl_xor(a3, 16); a3 += __shfl_xor(a3, 32);
    if (seg == 0 && act) {
        float inv = 1.0f / fmaxf((float)deg, 1.0f);
        size_t o = (size_t)node * 40 + dl * 4;
        ushort4 tv = *(const ushort4*)&t[o];
        float4 ov;
        ov.x = a0 * inv + b2f(tv.x);
        ov.y = a1 * inv + b2f(tv.y);
        ov.z = a2 * inv + b2f(tv.z);
        ov.w = a3 * inv + b2f(tv.w);
        *(float4*)&out[o] = ov;
    }
}

// ------------------------------------------------------------------- launch
extern "C" void kernel_launch(void* const* d_in, const int* in_sizes, int n_in,
                              void* d_out, int out_size, void* d_ws, size_t ws_size,
                              hipStream_t stream) {
    const float* x   = (const float*)d_in[0];
    const int*   ei  = (const int*)d_in[1];
    const int*   src = ei;
    const int*   dst = ei + NE;
    const float* W1l = (const float*)d_in[2];
    const float* b1  = (const float*)d_in[3];
    const float* W1r = (const float*)d_in[4];
    const float* W2l = (const float*)d_in[5];
    const float* b2  = (const float*)d_in[6];
    const float* W2r = (const float*)d_in[7];
    float* out = (float*)d_out;

    size_t off = 0;
    char* base = (char*)d_ws;
    auto alloc = [&](size_t bytes) -> void* {
        void* p = base + off;
        off += (bytes + 255) & ~(size_t)255;
        return p;
    };
    int*     deg32 = (int*)alloc((size_t)NCHK * NN * 4);
    int*     rp    = (int*)alloc((size_t)(NN + 1) * 4);
    int*     rpp   = (int*)alloc((size_t)NCHK * NN * 4);
    int*     col   = (int*)alloc((size_t)NE * 4);
    int*     bsum  = (int*)alloc(512 * 4);
    ushortT* Ac    = (ushortT*)alloc((size_t)NNP * 256 * 2);   // [agg|x] bf16
    ushortT* y2    = (ushortT*)alloc((size_t)NNP * 40 * 2);
    ushortT* t     = (ushortT*)alloc((size_t)NNP * 40 * 2);
    ushortT* WT1   = (ushortT*)alloc(256 * 256 * 2);
    ushortT* WT2   = (ushortT*)alloc(80 * 256 * 2);

    k_prep<<<12500 + NCHK * NSLI, 256, 0, stream>>>(x, W1l, W1r, W2l, W2r,
                                                    Ac, WT1, WT2, dst, deg32);
    k_scan1<<<NB1, 256, 0, stream>>>(deg32, rp, rpp, bsum);
    k_scan2<<<1, 512, 0, stream>>>(bsum);
    k_fillB<<<NCHK * NSLI, 256, 0, stream>>>(src, dst, rpp, bsum, col);
    k_agg1<<<(NN + 3) / 4, 256, 0, stream>>>(rp, bsum, col, Ac);
    k_fused<<<NNP / 64, 256, 0, stream>>>(Ac, WT1, b1, WT2, b2, y2, t);
    k_agg2<<<(NN + 3) / 4, 256, 0, stream>>>(rp, bsum, col, y2, t, out);
}